// Round 5
// baseline (589.040 us; speedup 1.0000x reference)
//
#include <hip/hip_runtime.h>
#include <cstdint>

#define C_DIM 1024
#define T_DIM 2048
#define B_DIM 4
#define FFN_DIM 4096
#define NROWS (B_DIM * T_DIM)                 // 8192 rows (B*T)
#define NELEM ((size_t)NROWS * C_DIM)
#define MB ((size_t)1 << 20)
#define NSEG 32
#define SEGL (T_DIM / NSEG)                   // 64

typedef __bf16 bf16;
typedef _Float16 f16;
typedef __bf16 bf16x4 __attribute__((ext_vector_type(4)));
typedef __bf16 bf16x8 __attribute__((ext_vector_type(8)));
typedef float  floatx4 __attribute__((ext_vector_type(4)));

// async global->LDS, 16B per lane; LDS dest is wave-uniform base + lane*16
#define GLDS(g, l) __builtin_amdgcn_global_load_lds(                          \
    (const __attribute__((address_space(1))) void*)(g),                       \
    (__attribute__((address_space(3))) void*)(l), 16, 0, 0)

// ---------------------------------------------------------------------------
// All 7 weight fp32->bf16 conversions in ONE dispatch.
// ---------------------------------------------------------------------------
struct W7 {
    const float* s[7];
    bf16*        d[7];
    int          cum[8];   // cumulative float4 counts, cum[7] = total
};

__global__ __launch_bounds__(256) void f2b7_kernel(W7 w)
{
    int id = blockIdx.x * 256 + threadIdx.x;
    int seg = 0;
#pragma unroll
    for (int j = 1; j < 7; ++j) if (id >= w.cum[j]) seg = j;
    int i = id - w.cum[seg];
    float4 v = ((const float4*)w.s[seg])[i];
    bf16x4 o = { (bf16)v.x, (bf16)v.y, (bf16)v.z, (bf16)v.w };
    ((bf16x4*)w.d[seg])[i] = o;
}

// ---------------------------------------------------------------------------
// Fused LayerNorm + token-shift mix (recomputes LN of row t-1 in-block).
// ---------------------------------------------------------------------------
template<bool HASV>
__global__ __launch_bounds__(256) void lnmix_kernel(const float* __restrict__ x,
                                                    const float* __restrict__ g,
                                                    const float* __restrict__ b,
                                                    const float* __restrict__ mk,
                                                    const float* __restrict__ mv,
                                                    const float* __restrict__ mr,
                                                    bf16* __restrict__ xk,
                                                    bf16* __restrict__ xv,
                                                    bf16* __restrict__ xr)
{
    int row = blockIdx.x;
    int t   = row & (T_DIM - 1);
    int tid = threadIdx.x;
    size_t i4 = (size_t)row * 256 + tid;

    float4 v  = ((const float4*)x)[i4];
    float4 vp = make_float4(0.f, 0.f, 0.f, 0.f);
    if (t != 0) vp = ((const float4*)x)[i4 - 256];

    float s   = v.x + v.y + v.z + v.w;
    float s2  = v.x * v.x + v.y * v.y + v.z * v.z + v.w * v.w;
    float sp  = vp.x + vp.y + vp.z + vp.w;
    float sp2 = vp.x * vp.x + vp.y * vp.y + vp.z * vp.z + vp.w * vp.w;
    for (int off = 32; off > 0; off >>= 1) {
        s   += __shfl_down(s,   off);
        s2  += __shfl_down(s2,  off);
        sp  += __shfl_down(sp,  off);
        sp2 += __shfl_down(sp2, off);
    }
    __shared__ float red[16];
    int lane = tid & 63, wid = tid >> 6;
    if (lane == 0) { red[wid] = s; red[4 + wid] = s2; red[8 + wid] = sp; red[12 + wid] = sp2; }
    __syncthreads();
    s   = red[0] + red[1] + red[2] + red[3];
    s2  = red[4] + red[5] + red[6] + red[7];
    sp  = red[8] + red[9] + red[10] + red[11];
    sp2 = red[12] + red[13] + red[14] + red[15];

    float mean  = s * (1.0f / C_DIM);
    float inv   = rsqrtf(s2 * (1.0f / C_DIM) - mean * mean + 1e-5f);
    float meanp = sp * (1.0f / C_DIM);
    float invp  = rsqrtf(sp2 * (1.0f / C_DIM) - meanp * meanp + 1e-5f);

    float4 gv = ((const float4*)g)[tid];
    float4 bv = ((const float4*)b)[tid];
    float4 hv, hp;
    hv.x = (v.x - mean) * inv * gv.x + bv.x;
    hv.y = (v.y - mean) * inv * gv.y + bv.y;
    hv.z = (v.z - mean) * inv * gv.z + bv.z;
    hv.w = (v.w - mean) * inv * gv.w + bv.w;
    if (t != 0) {
        hp.x = (vp.x - meanp) * invp * gv.x + bv.x;
        hp.y = (vp.y - meanp) * invp * gv.y + bv.y;
        hp.z = (vp.z - meanp) * invp * gv.z + bv.z;
        hp.w = (vp.w - meanp) * invp * gv.w + bv.w;
    } else {
        hp = make_float4(0.f, 0.f, 0.f, 0.f);
    }

    float4 m1 = ((const float4*)mk)[tid];
    bf16x4 o;
    o.x = (bf16)(hp.x + m1.x * (hv.x - hp.x));
    o.y = (bf16)(hp.y + m1.y * (hv.y - hp.y));
    o.z = (bf16)(hp.z + m1.z * (hv.z - hp.z));
    o.w = (bf16)(hp.w + m1.w * (hv.w - hp.w));
    ((bf16x4*)xk)[i4] = o;

    if (HASV) {
        float4 m2 = ((const float4*)mv)[tid];
        o.x = (bf16)(hp.x + m2.x * (hv.x - hp.x));
        o.y = (bf16)(hp.y + m2.y * (hv.y - hp.y));
        o.z = (bf16)(hp.z + m2.z * (hv.z - hp.z));
        o.w = (bf16)(hp.w + m2.w * (hv.w - hp.w));
        ((bf16x4*)xv)[i4] = o;
    }

    float4 m3 = ((const float4*)mr)[tid];
    o.x = (bf16)(hp.x + m3.x * (hv.x - hp.x));
    o.y = (bf16)(hp.y + m3.y * (hv.y - hp.y));
    o.z = (bf16)(hp.z + m3.z * (hv.z - hp.z));
    o.w = (bf16)(hp.w + m3.w * (hv.w - hp.w));
    ((bf16x4*)xr)[i4] = o;
}

// ---------------------------------------------------------------------------
// Grouped bf16 MFMA TN GEMM: up to 4 independent GEMMs in one dispatch.
// Per-GEMM: Y[8192,N] = epi( A[8192,K] @ W[N,K]^T ), 128x128 tile, BK=32,
// 256 thr (4 waves, 2x2 of 64x64), 16x16x32 MFMA, fp32 accumulate.
// LDS swizzle (R4, verified conflict-free): cell (r,q) at r*32+((q+(r>>1))&3)*8.
// XCD mapping: m-stripe per XCD (id&7 owns 8 m-tiles x all n-tiles) -> A is
// fetched ~once per XCD instead of ~8x (R4 n-stripe mapping over-fetched A).
// ---------------------------------------------------------------------------
#define EPI_NONE 0
#define EPI_SIG 1
#define EPI_RELU2 2
#define EPI_ADD 3
#define EPI_SCALEADD 4
// outk: 0=f32 1=bf16 2=f16

struct GArgs {
    const bf16*  A[4];
    const bf16*  W[4];
    void*        Y[4];
    const float* X2[4];
    const bf16*  S[4];
    int N[4], K[4], epi[4], outk[4], blk0[4];
    int ng;
};

__global__ __launch_bounds__(256) void gemm_grouped(GArgs G)
{
    __shared__ unsigned short As[128 * 32];   // 8 KB, swizzled layout
    __shared__ unsigned short Bs[128 * 32];

    int id = blockIdx.x;
    int gi = 0;
#pragma unroll
    for (int j = 1; j < 4; ++j) if (j < G.ng && id >= G.blk0[j]) gi = j;

    const bf16* A = G.A[gi];
    const bf16* W = G.W[gi];
    int N = G.N[gi], K = G.K[gi];
    int lid = id - G.blk0[gi];

    // m-stripe-per-XCD mapping: xcd owns m-tiles [xcd*8, xcd*8+8), n slow.
    int xcd = lid & 7, r = lid >> 3;
    int m_t = xcd * 8 + (r & 7);
    int n_t = r >> 3;                          // [0, N/128)
    int m0 = m_t << 7, n0 = n_t << 7;

    int tid = threadIdx.x;
    // staging: lane writes LDS at (wave base + lane*16B); source swizzled quad
    int r0  = tid >> 2;                               // rows 0..63 (chunk0)
    int qsw = ((tid & 3) - ((r0 >> 1) & 3)) & 3;      // rotated k-quad
    const bf16* Ag = A + (size_t)(m0 + r0) * K + qsw * 8;
    const bf16* Wg = W + (size_t)(n0 + r0) * K + qsw * 8;
    size_t rowK = (size_t)64 * K;
    int wv = tid >> 6;
    unsigned short* AsW0 = As + wv * 512;             // wave-uniform LDS bases
    unsigned short* AsW1 = As + 2048 + wv * 512;
    unsigned short* BsW0 = Bs + wv * 512;
    unsigned short* BsW1 = Bs + 2048 + wv * 512;

    int ln = tid & 63;
    int wm = (wv & 1) * 64, wn = (wv >> 1) * 64;
    int ra0 = wm + (ln & 15);
    int rb0 = wn + (ln & 15);
    int qa  = ln >> 4;
    int abase = ra0 * 32 + (((qa + (ra0 >> 1)) & 3) * 8);  // swizzled read addr
    int bbase = rb0 * 32 + (((qa + (rb0 >> 1)) & 3) * 8);

    floatx4 acc[4][4] = {};

    for (int k0 = 0; k0 < K; k0 += 32) {
        if (k0) __syncthreads();                 // LDS consumed by prev iter
        GLDS(Ag + k0,        AsW0);
        GLDS(Ag + k0 + rowK, AsW1);
        GLDS(Wg + k0,        BsW0);
        GLDS(Wg + k0 + rowK, BsW1);
        __syncthreads();                         // vmcnt(0) drain + barrier

        bf16x8 a[4], b[4];
#pragma unroll
        for (int i = 0; i < 4; ++i) a[i] = *(const bf16x8*)(As + abase + i * 512);
#pragma unroll
        for (int j = 0; j < 4; ++j) b[j] = *(const bf16x8*)(Bs + bbase + j * 512);
#pragma unroll
        for (int i = 0; i < 4; ++i)
#pragma unroll
            for (int j = 0; j < 4; ++j)
                acc[i][j] = __builtin_amdgcn_mfma_f32_16x16x32_bf16(a[i], b[j], acc[i][j], 0, 0, 0);
    }

    // epilogue (runtime epi/outk; block-uniform branches)
    int epi = G.epi[gi], outk = G.outk[gi];
    const float* X2 = G.X2[gi];
    const bf16*  S  = G.S[gi];
    float* Yf = (float*)G.Y[gi];
    bf16*  Yh = (bf16*)G.Y[gi];
    f16*   Ye = (f16*)G.Y[gi];

    // C/D layout (m89-verified): col = lane&15, row = (lane>>4)*4 + reg
    int row0 = (ln >> 4) * 4;
    int colb = n0 + wn + (ln & 15);
#pragma unroll
    for (int i = 0; i < 4; ++i) {
        int gm = m0 + wm + i * 16 + row0;
#pragma unroll
        for (int j = 0; j < 4; ++j) {
            int gn = colb + j * 16;
#pragma unroll
            for (int rr = 0; rr < 4; ++rr) {
                size_t idx = (size_t)(gm + rr) * N + gn;
                float v = acc[i][j][rr];
                if (epi == EPI_SIG)        v = 1.0f / (1.0f + __expf(-v));
                else if (epi == EPI_RELU2) { float t = fmaxf(v, 0.0f); v = t * t; }
                else if (epi == EPI_ADD)   v = X2[idx] + v;
                else if (epi == EPI_SCALEADD) v = X2[idx] + (float)S[idx] * v;
                if (outk == 0)      Yf[idx] = v;
                else if (outk == 1) Yh[idx] = (bf16)v;
                else                Ye[idx] = (f16)v;
            }
        }
    }
}

// ---------------------------------------------------------------------------
// WKV segmented scan (3 passes), log-space stabilized state (aa,bb)*e^pp.
// k, v stored fp16 (|k|,|v| ~ O(1); rel err ~1e-3, well under bf16 GEMM err).
// ---------------------------------------------------------------------------
__global__ __launch_bounds__(256) void wkv_seg(const f16* __restrict__ k,
                                               const f16* __restrict__ v,
                                               const float* __restrict__ decay,
                                               float* __restrict__ sa,
                                               float* __restrict__ sb,
                                               float* __restrict__ sp)
{
    int idx = blockIdx.x * 256 + threadIdx.x;   // (b*NSEG+seg)*C + c
    int c   = idx & (C_DIM - 1);
    int bs  = idx >> 10;
    int seg = bs & (NSEG - 1);
    int b   = bs >> 5;
    float w = -__expf(decay[c]);
    size_t base = ((size_t)b * T_DIM + (size_t)seg * SEGL) * C_DIM + c;
    float aa = 0.f, bb = 0.f, pp = -1e38f;
    for (int t = 0; t < SEGL; ++t) {
        size_t off = base + (size_t)t * C_DIM;
        float kk = (float)k[off], vv = (float)v[off];
        float ww2 = pp + w;
        float p2  = fmaxf(ww2, kk);
        float e1  = __expf(ww2 - p2);
        float e2  = __expf(kk - p2);
        aa = e1 * aa + e2 * vv;
        bb = e1 * bb + e2;
        pp = p2;
    }
    sa[idx] = aa; sb[idx] = bb; sp[idx] = pp;
}

__global__ __launch_bounds__(256) void wkv_comb(const float* __restrict__ sa,
                                                const float* __restrict__ sb,
                                                const float* __restrict__ sp,
                                                const float* __restrict__ decay,
                                                float* __restrict__ ia,
                                                float* __restrict__ ib,
                                                float* __restrict__ ip)
{
    int idx = blockIdx.x * 256 + threadIdx.x;   // b*C + c
    int c = idx & (C_DIM - 1);
    int b = idx >> 10;
    float wL = -__expf(decay[c]) * (float)SEGL;
    float aa = 0.f, bb = 0.f, pp = -1e38f;
    size_t base = (size_t)b * NSEG * C_DIM + c;
    for (int j = 0; j < NSEG; ++j) {
        size_t o = base + (size_t)j * C_DIM;
        ia[o] = aa; ib[o] = bb; ip[o] = pp;     // incoming state for segment j
        float a_s = sa[o], b_s = sb[o], p_s = sp[o];
        float pd = pp + wL;
        float pn = fmaxf(pd, p_s);
        float e1 = __expf(pd - pn);
        float e2 = __expf(p_s - pn);
        aa = e1 * aa + e2 * a_s;
        bb = e1 * bb + e2 * b_s;
        pp = pn;
    }
}

__global__ __launch_bounds__(256) void wkv_out(const f16* __restrict__ k,
                                               const f16* __restrict__ v,
                                               const bf16* __restrict__ sr,
                                               const float* __restrict__ decay,
                                               const float* __restrict__ first,
                                               const float* __restrict__ ia,
                                               const float* __restrict__ ib,
                                               const float* __restrict__ ip,
                                               bf16* __restrict__ out)
{
    int idx = blockIdx.x * 256 + threadIdx.x;   // (b*NSEG+seg)*C + c
    int c   = idx & (C_DIM - 1);
    int bs  = idx >> 10;
    int seg = bs & (NSEG - 1);
    int b   = bs >> 5;
    float w = -__expf(decay[c]);
    float u = first[c];
    float aa = ia[idx], bb = ib[idx], pp = ip[idx];
    size_t base = ((size_t)b * T_DIM + (size_t)seg * SEGL) * C_DIM + c;
    for (int t = 0; t < SEGL; ++t) {
        size_t off = base + (size_t)t * C_DIM;
        float kk = (float)k[off], vv = (float)v[off];
        float ww = u + kk;
        float p  = fmaxf(pp, ww);
        float e1 = __expf(pp - p);
        float e2 = __expf(ww - p);
        float o  = (e1 * aa + e2 * vv) / (e1 * bb + e2);
        out[off] = (bf16)((float)sr[off] * o);
        float ww2 = pp + w;
        float p2  = fmaxf(ww2, kk);
        float e1b = __expf(ww2 - p2);
        float e2b = __expf(kk - p2);
        aa = e1b * aa + e2b * vv;
        bb = e1b * bb + e2b;
        pp = p2;
    }
}

// ---------------------------------------------------------------------------
// Orchestration. Workspace (byte offsets, 189 MiB peak):
//   [0,26M)    bf16 weights: kw vw rw ow 2M ea | f_kw 8M | f_rw 2M | f_vw 8M
//   [26,74M)   bf16 acts: xk xv xr (16M ea) -> rwkv | xk2 xr2 sr2
//   [74,106M)  f16 k (16M), f16 v (16M)
//   [106,122M) bf16 sr (16M)
//   [122,186M) bf16 kk (64M, ChannelMix only; k/v/sr dead by then)
//   [186,189M) WKV scan scratch: 6 x 512 KiB
// ---------------------------------------------------------------------------
extern "C" void kernel_launch(void* const* d_in, const int* in_sizes, int n_in,
                              void* d_out, int out_size, void* d_ws, size_t ws_size,
                              hipStream_t stream)
{
    const float* x          = (const float*)d_in[0];
    const float* ln1_w      = (const float*)d_in[1];
    const float* ln1_b      = (const float*)d_in[2];
    const float* ln2_w      = (const float*)d_in[3];
    const float* ln2_b      = (const float*)d_in[4];
    const float* time_decay = (const float*)d_in[5];
    const float* time_first = (const float*)d_in[6];
    const float* tmk        = (const float*)d_in[7];
    const float* tmv        = (const float*)d_in[8];
    const float* tmr        = (const float*)d_in[9];
    const float* att_kw     = (const float*)d_in[10];
    const float* att_vw     = (const float*)d_in[11];
    const float* att_rw     = (const float*)d_in[12];
    const float* att_ow     = (const float*)d_in[13];
    const float* f_tmk      = (const float*)d_in[14];
    const float* f_tmr      = (const float*)d_in[15];
    const float* f_kw       = (const float*)d_in[16];
    const float* f_rw       = (const float*)d_in[17];
    const float* f_vw       = (const float*)d_in[18];
    float* out = (float*)d_out;

    char* W8 = (char*)d_ws;
    bf16* kw_b  = (bf16*)(W8 + 0 * MB);
    bf16* vw_b  = (bf16*)(W8 + 2 * MB);
    bf16* rw_b  = (bf16*)(W8 + 4 * MB);
    bf16* ow_b  = (bf16*)(W8 + 6 * MB);
    bf16* fkw_b = (bf16*)(W8 + 8 * MB);
    bf16* frw_b = (bf16*)(W8 + 16 * MB);
    bf16* fvw_b = (bf16*)(W8 + 18 * MB);

    bf16*  xk_b   = (bf16*)(W8 + 26 * MB);
    bf16*  xv_b   = (bf16*)(W8 + 42 * MB);
    bf16*  xr_b   = (bf16*)(W8 + 58 * MB);
    bf16*  rwkv_b = xk_b;                       // reuse after kvr-GEMM consumes xk
    bf16*  xk2_b  = (bf16*)(W8 + 26 * MB);
    bf16*  xr2_b  = (bf16*)(W8 + 42 * MB);
    bf16*  sr2_b  = (bf16*)(W8 + 58 * MB);
    f16*   kbuf   = (f16*)(W8 + 74 * MB);
    f16*   vbuf   = (f16*)(W8 + 90 * MB);
    bf16*  srb_b  = (bf16*)(W8 + 106 * MB);
    bf16*  kk_b   = (bf16*)(W8 + 122 * MB);     // [122,186), ChannelMix phase only

    size_t KB512 = (size_t)512 * 1024;
    float* sc_a = (float*)(W8 + 186 * MB);
    float* sc_b = (float*)(W8 + 186 * MB + 1 * KB512);
    float* sc_p = (float*)(W8 + 186 * MB + 2 * KB512);
    float* in_a = (float*)(W8 + 186 * MB + 3 * KB512);
    float* in_b = (float*)(W8 + 186 * MB + 4 * KB512);
    float* in_p = (float*)(W8 + 186 * MB + 5 * KB512);

    // single-dispatch weight conversion
    int nC4 = C_DIM * C_DIM / 4, nF4 = FFN_DIM * C_DIM / 4;
    W7 w7;
    const float* srcs[7] = { att_kw, att_vw, att_rw, att_ow, f_kw, f_rw, f_vw };
    bf16*        dsts[7] = { kw_b, vw_b, rw_b, ow_b, fkw_b, frw_b, fvw_b };
    int          cnts[7] = { nC4, nC4, nC4, nC4, nF4, nC4, nF4 };
    int cum = 0;
    for (int i = 0; i < 7; ++i) { w7.s[i] = srcs[i]; w7.d[i] = dsts[i]; w7.cum[i] = cum; cum += cnts[i]; }
    w7.cum[7] = cum;                                   // 3407872, /256 = 13312
    f2b7_kernel<<<cum / 256, 256, 0, stream>>>(w7);

    auto mkdesc = [](GArgs& G, int& total, const bf16* A, const bf16* W, void* Y,
                     const float* X2, const bf16* S, int N, int K, int epi, int outk) {
        int i = G.ng;
        G.A[i] = A; G.W[i] = W; G.Y[i] = Y; G.X2[i] = X2; G.S[i] = S;
        G.N[i] = N; G.K[i] = K; G.epi[i] = epi; G.outk[i] = outk;
        G.blk0[i] = total; total += 64 * (N >> 7); G.ng = i + 1;
    };

    int segGrid = B_DIM * NSEG * C_DIM / 256;   // 512

    // --- TimeMix ---
    lnmix_kernel<true><<<NROWS, 256, 0, stream>>>(x, ln1_w, ln1_b, tmk, tmv, tmr,
                                                  xk_b, xv_b, xr_b);
    {   // grouped k,v,r GEMMs: 1536 blocks, one dispatch
        GArgs G = {}; int total = 0;
        mkdesc(G, total, xk_b, kw_b, kbuf,  nullptr, nullptr, C_DIM, C_DIM, EPI_NONE, 2);
        mkdesc(G, total, xv_b, vw_b, vbuf,  nullptr, nullptr, C_DIM, C_DIM, EPI_NONE, 2);
        mkdesc(G, total, xr_b, rw_b, srb_b, nullptr, nullptr, C_DIM, C_DIM, EPI_SIG,  1);
        gemm_grouped<<<total, 256, 0, stream>>>(G);
    }
    wkv_seg<<<segGrid, 256, 0, stream>>>(kbuf, vbuf, time_decay, sc_a, sc_b, sc_p);
    wkv_comb<<<B_DIM * C_DIM / 256, 256, 0, stream>>>(sc_a, sc_b, sc_p, time_decay, in_a, in_b, in_p);
    wkv_out<<<segGrid, 256, 0, stream>>>(kbuf, vbuf, srb_b, time_decay, time_first,
                                         in_a, in_b, in_p, rwkv_b);
    {   // ow GEMM + residual
        GArgs G = {}; int total = 0;
        mkdesc(G, total, rwkv_b, ow_b, out, x, nullptr, C_DIM, C_DIM, EPI_ADD, 0);
        gemm_grouped<<<total, 256, 0, stream>>>(G);
    }

    // --- ChannelMix ---
    lnmix_kernel<false><<<NROWS, 256, 0, stream>>>(out, ln2_w, ln2_b, f_tmk, nullptr, f_tmr,
                                                   xk2_b, nullptr, xr2_b);
    {   // grouped f_rw (sigmoid) + FFN-up (relu^2): 2560 blocks
        GArgs G = {}; int total = 0;
        mkdesc(G, total, xr2_b, frw_b, sr2_b, nullptr, nullptr, C_DIM,   C_DIM, EPI_SIG,   1);
        mkdesc(G, total, xk2_b, fkw_b, kk_b,  nullptr, nullptr, FFN_DIM, C_DIM, EPI_RELU2, 1);
        gemm_grouped<<<total, 256, 0, stream>>>(G);
    }
    {   // FFN-down + gated residual
        GArgs G = {}; int total = 0;
        mkdesc(G, total, kk_b, fvw_b, out, out, sr2_b, C_DIM, FFN_DIM, EPI_SCALEADD, 0);
        gemm_grouped<<<total, 256, 0, stream>>>(G);
    }
}

// Round 6
// 568.761 us; speedup vs baseline: 1.0357x; 1.0357x over previous
//
#include <hip/hip_runtime.h>
#include <cstdint>

#define C_DIM 1024
#define T_DIM 2048
#define B_DIM 4
#define FFN_DIM 4096
#define NROWS (B_DIM * T_DIM)                 // 8192 rows (B*T)
#define NELEM ((size_t)NROWS * C_DIM)
#define MB ((size_t)1 << 20)
#define NSEG 32
#define SEGL (T_DIM / NSEG)                   // 64

typedef __bf16 bf16;
typedef _Float16 f16;
typedef __bf16 bf16x4 __attribute__((ext_vector_type(4)));
typedef __bf16 bf16x8 __attribute__((ext_vector_type(8)));
typedef float  floatx4 __attribute__((ext_vector_type(4)));

// async global->LDS, 16B per lane; LDS dest is wave-uniform base + lane*16
#define GLDS(g, l) __builtin_amdgcn_global_load_lds(                          \
    (const __attribute__((address_space(1))) void*)(g),                       \
    (__attribute__((address_space(3))) void*)(l), 16, 0, 0)

// ---------------------------------------------------------------------------
// All 7 weight fp32->bf16 conversions in ONE dispatch.
// ---------------------------------------------------------------------------
struct W7 {
    const float* s[7];
    bf16*        d[7];
    int          cum[8];   // cumulative float4 counts, cum[7] = total
};

__global__ __launch_bounds__(256) void f2b7_kernel(W7 w)
{
    int id = blockIdx.x * 256 + threadIdx.x;
    int seg = 0;
#pragma unroll
    for (int j = 1; j < 7; ++j) if (id >= w.cum[j]) seg = j;
    int i = id - w.cum[seg];
    float4 v = ((const float4*)w.s[seg])[i];
    bf16x4 o = { (bf16)v.x, (bf16)v.y, (bf16)v.z, (bf16)v.w };
    ((bf16x4*)w.d[seg])[i] = o;
}

// ---------------------------------------------------------------------------
// Fused LayerNorm + token-shift mix (recomputes LN of row t-1 in-block).
// ---------------------------------------------------------------------------
template<bool HASV>
__global__ __launch_bounds__(256) void lnmix_kernel(const float* __restrict__ x,
                                                    const float* __restrict__ g,
                                                    const float* __restrict__ b,
                                                    const float* __restrict__ mk,
                                                    const float* __restrict__ mv,
                                                    const float* __restrict__ mr,
                                                    bf16* __restrict__ xk,
                                                    bf16* __restrict__ xv,
                                                    bf16* __restrict__ xr)
{
    int row = blockIdx.x;
    int t   = row & (T_DIM - 1);
    int tid = threadIdx.x;
    size_t i4 = (size_t)row * 256 + tid;

    float4 v  = ((const float4*)x)[i4];
    float4 vp = make_float4(0.f, 0.f, 0.f, 0.f);
    if (t != 0) vp = ((const float4*)x)[i4 - 256];

    float s   = v.x + v.y + v.z + v.w;
    float s2  = v.x * v.x + v.y * v.y + v.z * v.z + v.w * v.w;
    float sp  = vp.x + vp.y + vp.z + vp.w;
    float sp2 = vp.x * vp.x + vp.y * vp.y + vp.z * vp.z + vp.w * vp.w;
    for (int off = 32; off > 0; off >>= 1) {
        s   += __shfl_down(s,   off);
        s2  += __shfl_down(s2,  off);
        sp  += __shfl_down(sp,  off);
        sp2 += __shfl_down(sp2, off);
    }
    __shared__ float red[16];
    int lane = tid & 63, wid = tid >> 6;
    if (lane == 0) { red[wid] = s; red[4 + wid] = s2; red[8 + wid] = sp; red[12 + wid] = sp2; }
    __syncthreads();
    s   = red[0] + red[1] + red[2] + red[3];
    s2  = red[4] + red[5] + red[6] + red[7];
    sp  = red[8] + red[9] + red[10] + red[11];
    sp2 = red[12] + red[13] + red[14] + red[15];

    float mean  = s * (1.0f / C_DIM);
    float inv   = rsqrtf(s2 * (1.0f / C_DIM) - mean * mean + 1e-5f);
    float meanp = sp * (1.0f / C_DIM);
    float invp  = rsqrtf(sp2 * (1.0f / C_DIM) - meanp * meanp + 1e-5f);

    float4 gv = ((const float4*)g)[tid];
    float4 bv = ((const float4*)b)[tid];
    float4 hv, hp;
    hv.x = (v.x - mean) * inv * gv.x + bv.x;
    hv.y = (v.y - mean) * inv * gv.y + bv.y;
    hv.z = (v.z - mean) * inv * gv.z + bv.z;
    hv.w = (v.w - mean) * inv * gv.w + bv.w;
    if (t != 0) {
        hp.x = (vp.x - meanp) * invp * gv.x + bv.x;
        hp.y = (vp.y - meanp) * invp * gv.y + bv.y;
        hp.z = (vp.z - meanp) * invp * gv.z + bv.z;
        hp.w = (vp.w - meanp) * invp * gv.w + bv.w;
    } else {
        hp = make_float4(0.f, 0.f, 0.f, 0.f);
    }

    float4 m1 = ((const float4*)mk)[tid];
    bf16x4 o;
    o.x = (bf16)(hp.x + m1.x * (hv.x - hp.x));
    o.y = (bf16)(hp.y + m1.y * (hv.y - hp.y));
    o.z = (bf16)(hp.z + m1.z * (hv.z - hp.z));
    o.w = (bf16)(hp.w + m1.w * (hv.w - hp.w));
    ((bf16x4*)xk)[i4] = o;

    if (HASV) {
        float4 m2 = ((const float4*)mv)[tid];
        o.x = (bf16)(hp.x + m2.x * (hv.x - hp.x));
        o.y = (bf16)(hp.y + m2.y * (hv.y - hp.y));
        o.z = (bf16)(hp.z + m2.z * (hv.z - hp.z));
        o.w = (bf16)(hp.w + m2.w * (hv.w - hp.w));
        ((bf16x4*)xv)[i4] = o;
    }

    float4 m3 = ((const float4*)mr)[tid];
    o.x = (bf16)(hp.x + m3.x * (hv.x - hp.x));
    o.y = (bf16)(hp.y + m3.y * (hv.y - hp.y));
    o.z = (bf16)(hp.z + m3.z * (hv.z - hp.z));
    o.w = (bf16)(hp.w + m3.w * (hv.w - hp.w));
    ((bf16x4*)xr)[i4] = o;
}

// ---------------------------------------------------------------------------
// Grouped bf16 MFMA TN GEMM, BK=64: Y[8192,N] = epi( A[8192,K] @ W[N,K]^T ).
// 128x128 tile, 256 thr (4 waves, 2x2 of 64x64), 16x16x32 MFMA, fp32 acc.
// BK=64 -> 32 MFMA + 16 ds_read_b128 per barrier-pair (2x the m97/BK=32
// density; amortizes the vmcnt(0) drain at each __syncthreads).
// LDS: rows of 64 ushort (128B = 8 chunks of 16B); cell (row, chunk q) at
// phys chunk q ^ (row&7)  ->  reader banks = phys only (row*128B = 0 mod 32
// banks), all 8 phys values hit all 32 banks, 2-way = free. Staging q_src =
// (ln&7)^((ln>>3)&7) is round-independent (rounds step rows by 32 = 0 mod 8)
// and keeps each 128B row segment fully covered -> coalesced.
// XCD mapping: m-stripe per XCD (R5, FETCH-verified).
// ---------------------------------------------------------------------------
#define EPI_NONE 0
#define EPI_SIG 1
#define EPI_RELU2 2
#define EPI_ADD 3
#define EPI_SCALEADD 4
// outk: 0=f32 1=bf16 2=f16

struct GArgs {
    const bf16*  A[4];
    const bf16*  W[4];
    void*        Y[4];
    const float* X2[4];
    const bf16*  S[4];
    int N[4], K[4], epi[4], outk[4], blk0[4];
    int ng;
};

__global__ __launch_bounds__(256) void gemm_grouped(GArgs G)
{
    __shared__ unsigned short As[128 * 64];   // 16 KB, swizzled, BK=64
    __shared__ unsigned short Bs[128 * 64];

    int id = blockIdx.x;
    int gi = 0;
#pragma unroll
    for (int j = 1; j < 4; ++j) if (j < G.ng && id >= G.blk0[j]) gi = j;

    const bf16* A = G.A[gi];
    const bf16* W = G.W[gi];
    int N = G.N[gi], K = G.K[gi];
    int lid = id - G.blk0[gi];

    // m-stripe-per-XCD mapping: xcd owns m-tiles [xcd*8, xcd*8+8), n slow.
    int xcd = lid & 7, r = lid >> 3;
    int m_t = xcd * 8 + (r & 7);
    int n_t = r >> 3;                          // [0, N/128)
    int m0 = m_t << 7, n0 = n_t << 7;

    int tid = threadIdx.x;
    int wv = tid >> 6;
    int ln = tid & 63;

    // staging: round j covers rows j*32 + wv*8 + (ln>>3); lane's source chunk
    int qsrc = (ln & 7) ^ ((ln >> 3) & 7);
    const bf16* Ag = A + (size_t)(m0 + wv * 8 + (ln >> 3)) * K + qsrc * 8;
    const bf16* Wg = W + (size_t)(n0 + wv * 8 + (ln >> 3)) * K + qsrc * 8;
    size_t row32K = (size_t)32 * K;
    unsigned short* AsW = As + (wv * 8) * 64;        // wave-uniform LDS bases
    unsigned short* BsW = Bs + (wv * 8) * 64;

    int wm = (wv & 1) * 64, wn = (wv >> 1) * 64;
    // frag read offsets (ushorts): row*64 + (chunk ^ (row&7))*8,
    // row&7 = ln&7 (wm, i*16 are 0 mod 8), chunk = (ln>>4) + 4*s
    int arow = wm + (ln & 15);
    int brow = wn + (ln & 15);
    int q0 = (ln >> 4) ^ (ln & 7);
    int q1 = ((ln >> 4) + 4) ^ (ln & 7);
    int aoff0 = arow * 64 + q0 * 8, aoff1 = arow * 64 + q1 * 8;
    int boff0 = brow * 64 + q0 * 8, boff1 = brow * 64 + q1 * 8;

    floatx4 acc[4][4] = {};

    for (int k0 = 0; k0 < K; k0 += 64) {
        if (k0) __syncthreads();                 // LDS consumed by prev iter
#pragma unroll
        for (int j = 0; j < 4; ++j)
            GLDS(Ag + k0 + (size_t)j * row32K, AsW + j * 32 * 64);
#pragma unroll
        for (int j = 0; j < 4; ++j)
            GLDS(Wg + k0 + (size_t)j * row32K, BsW + j * 32 * 64);
        __syncthreads();                         // vmcnt(0) drain + barrier

        bf16x8 a0[4], a1[4], b0[4], b1[4];
#pragma unroll
        for (int i = 0; i < 4; ++i) {
            a0[i] = *(const bf16x8*)(As + aoff0 + i * 1024);
            a1[i] = *(const bf16x8*)(As + aoff1 + i * 1024);
        }
#pragma unroll
        for (int j = 0; j < 4; ++j) {
            b0[j] = *(const bf16x8*)(Bs + boff0 + j * 1024);
            b1[j] = *(const bf16x8*)(Bs + boff1 + j * 1024);
        }
#pragma unroll
        for (int i = 0; i < 4; ++i)
#pragma unroll
            for (int j = 0; j < 4; ++j)
                acc[i][j] = __builtin_amdgcn_mfma_f32_16x16x32_bf16(a0[i], b0[j], acc[i][j], 0, 0, 0);
#pragma unroll
        for (int i = 0; i < 4; ++i)
#pragma unroll
            for (int j = 0; j < 4; ++j)
                acc[i][j] = __builtin_amdgcn_mfma_f32_16x16x32_bf16(a1[i], b1[j], acc[i][j], 0, 0, 0);
    }

    // epilogue (runtime epi/outk; block-uniform branches)
    int epi = G.epi[gi], outk = G.outk[gi];
    const float* X2 = G.X2[gi];
    const bf16*  S  = G.S[gi];
    float* Yf = (float*)G.Y[gi];
    bf16*  Yh = (bf16*)G.Y[gi];
    f16*   Ye = (f16*)G.Y[gi];

    // C/D layout (m89-verified): col = lane&15, row = (lane>>4)*4 + reg
    int row0 = (ln >> 4) * 4;
    int colb = n0 + wn + (ln & 15);
#pragma unroll
    for (int i = 0; i < 4; ++i) {
        int gm = m0 + wm + i * 16 + row0;
#pragma unroll
        for (int j = 0; j < 4; ++j) {
            int gn = colb + j * 16;
#pragma unroll
            for (int rr = 0; rr < 4; ++rr) {
                size_t idx = (size_t)(gm + rr) * N + gn;
                float v = acc[i][j][rr];
                if (epi == EPI_SIG)        v = 1.0f / (1.0f + __expf(-v));
                else if (epi == EPI_RELU2) { float t = fmaxf(v, 0.0f); v = t * t; }
                else if (epi == EPI_ADD)   v = X2[idx] + v;
                else if (epi == EPI_SCALEADD) v = X2[idx] + (float)S[idx] * v;
                if (outk == 0)      Yf[idx] = v;
                else if (outk == 1) Yh[idx] = (bf16)v;
                else                Ye[idx] = (f16)v;
            }
        }
    }
}

// ---------------------------------------------------------------------------
// WKV segmented scan (3 passes), log-space stabilized state (aa,bb)*e^pp.
// k, v stored fp16 (|k|,|v| ~ O(1); rel err ~1e-3, under bf16 GEMM err).
// ---------------------------------------------------------------------------
__global__ __launch_bounds__(256) void wkv_seg(const f16* __restrict__ k,
                                               const f16* __restrict__ v,
                                               const float* __restrict__ decay,
                                               float* __restrict__ sa,
                                               float* __restrict__ sb,
                                               float* __restrict__ sp)
{
    int idx = blockIdx.x * 256 + threadIdx.x;   // (b*NSEG+seg)*C + c
    int c   = idx & (C_DIM - 1);
    int bs  = idx >> 10;
    int seg = bs & (NSEG - 1);
    int b   = bs >> 5;
    float w = -__expf(decay[c]);
    size_t base = ((size_t)b * T_DIM + (size_t)seg * SEGL) * C_DIM + c;
    float aa = 0.f, bb = 0.f, pp = -1e38f;
    for (int t = 0; t < SEGL; ++t) {
        size_t off = base + (size_t)t * C_DIM;
        float kk = (float)k[off], vv = (float)v[off];
        float ww2 = pp + w;
        float p2  = fmaxf(ww2, kk);
        float e1  = __expf(ww2 - p2);
        float e2  = __expf(kk - p2);
        aa = e1 * aa + e2 * vv;
        bb = e1 * bb + e2;
        pp = p2;
    }
    sa[idx] = aa; sb[idx] = bb; sp[idx] = pp;
}

__global__ __launch_bounds__(256) void wkv_comb(const float* __restrict__ sa,
                                                const float* __restrict__ sb,
                                                const float* __restrict__ sp,
                                                const float* __restrict__ decay,
                                                float* __restrict__ ia,
                                                float* __restrict__ ib,
                                                float* __restrict__ ip)
{
    int idx = blockIdx.x * 256 + threadIdx.x;   // b*C + c
    int c = idx & (C_DIM - 1);
    int b = idx >> 10;
    float wL = -__expf(decay[c]) * (float)SEGL;
    float aa = 0.f, bb = 0.f, pp = -1e38f;
    size_t base = (size_t)b * NSEG * C_DIM + c;
    for (int j = 0; j < NSEG; ++j) {
        size_t o = base + (size_t)j * C_DIM;
        ia[o] = aa; ib[o] = bb; ip[o] = pp;     // incoming state for segment j
        float a_s = sa[o], b_s = sb[o], p_s = sp[o];
        float pd = pp + wL;
        float pn = fmaxf(pd, p_s);
        float e1 = __expf(pd - pn);
        float e2 = __expf(p_s - pn);
        aa = e1 * aa + e2 * a_s;
        bb = e1 * bb + e2 * b_s;
        pp = pn;
    }
}

__global__ __launch_bounds__(256) void wkv_out(const f16* __restrict__ k,
                                               const f16* __restrict__ v,
                                               const bf16* __restrict__ sr,
                                               const float* __restrict__ decay,
                                               const float* __restrict__ first,
                                               const float* __restrict__ ia,
                                               const float* __restrict__ ib,
                                               const float* __restrict__ ip,
                                               bf16* __restrict__ out)
{
    int idx = blockIdx.x * 256 + threadIdx.x;   // (b*NSEG+seg)*C + c
    int c   = idx & (C_DIM - 1);
    int bs  = idx >> 10;
    int seg = bs & (NSEG - 1);
    int b   = bs >> 5;
    float w = -__expf(decay[c]);
    float u = first[c];
    float aa = ia[idx], bb = ib[idx], pp = ip[idx];
    size_t base = ((size_t)b * T_DIM + (size_t)seg * SEGL) * C_DIM + c;
    for (int t = 0; t < SEGL; ++t) {
        size_t off = base + (size_t)t * C_DIM;
        float kk = (float)k[off], vv = (float)v[off];
        float ww = u + kk;
        float p  = fmaxf(pp, ww);
        float e1 = __expf(pp - p);
        float e2 = __expf(ww - p);
        float o  = (e1 * aa + e2 * vv) / (e1 * bb + e2);
        out[off] = (bf16)((float)sr[off] * o);
        float ww2 = pp + w;
        float p2  = fmaxf(ww2, kk);
        float e1b = __expf(ww2 - p2);
        float e2b = __expf(kk - p2);
        aa = e1b * aa + e2b * vv;
        bb = e1b * bb + e2b;
        pp = p2;
    }
}

// ---------------------------------------------------------------------------
// Orchestration. Workspace (byte offsets, 189 MiB peak):
//   [0,26M)    bf16 weights: kw vw rw ow 2M ea | f_kw 8M | f_rw 2M | f_vw 8M
//   [26,74M)   bf16 acts: xk xv xr (16M ea) -> rwkv | xk2 xr2 sr2
//   [74,106M)  f16 k (16M), f16 v (16M)
//   [106,122M) bf16 sr (16M)
//   [122,186M) bf16 kk (64M, ChannelMix only; k/v/sr dead by then)
//   [186,189M) WKV scan scratch: 6 x 512 KiB
// ---------------------------------------------------------------------------
extern "C" void kernel_launch(void* const* d_in, const int* in_sizes, int n_in,
                              void* d_out, int out_size, void* d_ws, size_t ws_size,
                              hipStream_t stream)
{
    const float* x          = (const float*)d_in[0];
    const float* ln1_w      = (const float*)d_in[1];
    const float* ln1_b      = (const float*)d_in[2];
    const float* ln2_w      = (const float*)d_in[3];
    const float* ln2_b      = (const float*)d_in[4];
    const float* time_decay = (const float*)d_in[5];
    const float* time_first = (const float*)d_in[6];
    const float* tmk        = (const float*)d_in[7];
    const float* tmv        = (const float*)d_in[8];
    const float* tmr        = (const float*)d_in[9];
    const float* att_kw     = (const float*)d_in[10];
    const float* att_vw     = (const float*)d_in[11];
    const float* att_rw     = (const float*)d_in[12];
    const float* att_ow     = (const float*)d_in[13];
    const float* f_tmk      = (const float*)d_in[14];
    const float* f_tmr      = (const float*)d_in[15];
    const float* f_kw       = (const float*)d_in[16];
    const float* f_rw       = (const float*)d_in[17];
    const float* f_vw       = (const float*)d_in[18];
    float* out = (float*)d_out;

    char* W8 = (char*)d_ws;
    bf16* kw_b  = (bf16*)(W8 + 0 * MB);
    bf16* vw_b  = (bf16*)(W8 + 2 * MB);
    bf16* rw_b  = (bf16*)(W8 + 4 * MB);
    bf16* ow_b  = (bf16*)(W8 + 6 * MB);
    bf16* fkw_b = (bf16*)(W8 + 8 * MB);
    bf16* frw_b = (bf16*)(W8 + 16 * MB);
    bf16* fvw_b = (bf16*)(W8 + 18 * MB);

    bf16*  xk_b   = (bf16*)(W8 + 26 * MB);
    bf16*  xv_b   = (bf16*)(W8 + 42 * MB);
    bf16*  xr_b   = (bf16*)(W8 + 58 * MB);
    bf16*  rwkv_b = xk_b;                       // reuse after kvr-GEMM consumes xk
    bf16*  xk2_b  = (bf16*)(W8 + 26 * MB);
    bf16*  xr2_b  = (bf16*)(W8 + 42 * MB);
    bf16*  sr2_b  = (bf16*)(W8 + 58 * MB);
    f16*   kbuf   = (f16*)(W8 + 74 * MB);
    f16*   vbuf   = (f16*)(W8 + 90 * MB);
    bf16*  srb_b  = (bf16*)(W8 + 106 * MB);
    bf16*  kk_b   = (bf16*)(W8 + 122 * MB);     // [122,186), ChannelMix phase only

    size_t KB512 = (size_t)512 * 1024;
    float* sc_a = (float*)(W8 + 186 * MB);
    float* sc_b = (float*)(W8 + 186 * MB + 1 * KB512);
    float* sc_p = (float*)(W8 + 186 * MB + 2 * KB512);
    float* in_a = (float*)(W8 + 186 * MB + 3 * KB512);
    float* in_b = (float*)(W8 + 186 * MB + 4 * KB512);
    float* in_p = (float*)(W8 + 186 * MB + 5 * KB512);

    // single-dispatch weight conversion
    int nC4 = C_DIM * C_DIM / 4, nF4 = FFN_DIM * C_DIM / 4;
    W7 w7;
    const float* srcs[7] = { att_kw, att_vw, att_rw, att_ow, f_kw, f_rw, f_vw };
    bf16*        dsts[7] = { kw_b, vw_b, rw_b, ow_b, fkw_b, frw_b, fvw_b };
    int          cnts[7] = { nC4, nC4, nC4, nC4, nF4, nC4, nF4 };
    int cum = 0;
    for (int i = 0; i < 7; ++i) { w7.s[i] = srcs[i]; w7.d[i] = dsts[i]; w7.cum[i] = cum; cum += cnts[i]; }
    w7.cum[7] = cum;                                   // 3407872, /256 = 13312
    f2b7_kernel<<<cum / 256, 256, 0, stream>>>(w7);

    auto mkdesc = [](GArgs& G, int& total, const bf16* A, const bf16* W, void* Y,
                     const float* X2, const bf16* S, int N, int K, int epi, int outk) {
        int i = G.ng;
        G.A[i] = A; G.W[i] = W; G.Y[i] = Y; G.X2[i] = X2; G.S[i] = S;
        G.N[i] = N; G.K[i] = K; G.epi[i] = epi; G.outk[i] = outk;
        G.blk0[i] = total; total += 64 * (N >> 7); G.ng = i + 1;
    };

    int segGrid = B_DIM * NSEG * C_DIM / 256;   // 512

    // --- TimeMix ---
    lnmix_kernel<true><<<NROWS, 256, 0, stream>>>(x, ln1_w, ln1_b, tmk, tmv, tmr,
                                                  xk_b, xv_b, xr_b);
    {   // grouped k,v,r GEMMs: 1536 blocks, one dispatch
        GArgs G = {}; int total = 0;
        mkdesc(G, total, xk_b, kw_b, kbuf,  nullptr, nullptr, C_DIM, C_DIM, EPI_NONE, 2);
        mkdesc(G, total, xv_b, vw_b, vbuf,  nullptr, nullptr, C_DIM, C_DIM, EPI_NONE, 2);
        mkdesc(G, total, xr_b, rw_b, srb_b, nullptr, nullptr, C_DIM, C_DIM, EPI_SIG,  1);
        gemm_grouped<<<total, 256, 0, stream>>>(G);
    }
    wkv_seg<<<segGrid, 256, 0, stream>>>(kbuf, vbuf, time_decay, sc_a, sc_b, sc_p);
    wkv_comb<<<B_DIM * C_DIM / 256, 256, 0, stream>>>(sc_a, sc_b, sc_p, time_decay, in_a, in_b, in_p);
    wkv_out<<<segGrid, 256, 0, stream>>>(kbuf, vbuf, srb_b, time_decay, time_first,
                                         in_a, in_b, in_p, rwkv_b);
    {   // ow GEMM + residual
        GArgs G = {}; int total = 0;
        mkdesc(G, total, rwkv_b, ow_b, out, x, nullptr, C_DIM, C_DIM, EPI_ADD, 0);
        gemm_grouped<<<total, 256, 0, stream>>>(G);
    }

    // --- ChannelMix ---
    lnmix_kernel<false><<<NROWS, 256, 0, stream>>>(out, ln2_w, ln2_b, f_tmk, nullptr, f_tmr,
                                                   xk2_b, nullptr, xr2_b);
    {   // grouped f_rw (sigmoid) + FFN-up (relu^2): 2560 blocks
        GArgs G = {}; int total = 0;
        mkdesc(G, total, xr2_b, frw_b, sr2_b, nullptr, nullptr, C_DIM,   C_DIM, EPI_SIG,   1);
        mkdesc(G, total, xk2_b, fkw_b, kk_b,  nullptr, nullptr, FFN_DIM, C_DIM, EPI_RELU2, 1);
        gemm_grouped<<<total, 256, 0, stream>>>(G);
    }
    {   // FFN-down + gated residual
        GArgs G = {}; int total = 0;
        mkdesc(G, total, kk_b, fvw_b, out, out, sr2_b, C_DIM, FFN_DIM, EPI_SCALEADD, 0);
        gemm_grouped<<<total, 256, 0, stream>>>(G);
    }
}